// Round 11
// baseline (407.985 us; speedup 1.0000x reference)
//
#include <hip/hip_runtime.h>

// MGNConv fused-MFMA, round 11: one-tile SKEWED pipeline (ILP, not TLP).
//   edge_out[e,k] = sum_{c,ab} hs[e,c] * o[e,ab] * w2[c, ab*8+k]
//   hs = silu(emb@w1/4)/64,  o[e,ab] = attr[e,ab>>4] * z[e,ab&15]
// Round-10 post-mortem: occupancy pinned at 19% even at VGPR=104/LDS=78848;
// only VGPR=64 builds ever co-scheduled (hidden ~64-reg AGPR block =>
// effective regs ~arch+64 => 3 waves/SIMD at 104). Occupancy route CLOSED.
// ~50% of cycles issue nothing (VALUBusy 40 + MfmaUtil 21): C(t)->D(t) are
// dependent, so C latency is never hidden.
// Changes this round:
//  - skew one tile: iteration runs D(tile) with a2 from last iteration while
//    staging + C-phase of tile+nw are interleaved between D's g-groups:
//    S1 loads -> g0,g1 -> LDS write + a1 -> C(s0) -> g2 -> C(s1) -> g3 -> E
//  - double-buffered zt/at/vj per wave (LDS 92160 B; 1 block/CU anyway)
//  - a2 double-buffered in regs (+16); NBLK=256 (persistent, one w2 stage)
//  - s_setprio dropped (symmetric waves)

typedef __attribute__((ext_vector_type(8))) short short8;
typedef __attribute__((ext_vector_type(4))) float floatx4;

#define AI __attribute__((always_inline))

__device__ AI inline unsigned short f2bf(float f) {
    union { float f; unsigned u; } v; v.f = f;
    unsigned r = v.u + 0x7FFFu + ((v.u >> 16) & 1u);
    return (unsigned short)(r >> 16);
}
__device__ AI inline float bf2f(unsigned short u) {
    union { unsigned u; float f; } v; v.u = ((unsigned)u) << 16;
    return v.f;
}
__device__ AI inline unsigned cvt_pk_bf16(float lo, float hi) {
    unsigned r;
    asm("v_cvt_pk_bf16_f32 %0, %1, %2" : "=v"(r) : "v"(lo), "v"(hi));
    return r;
}

constexpr int TB    = 512;   // 8 waves
constexpr int NBLK  = 256;   // 1 persistent block per CU
constexpr int NWAVE = TB / 64;

// ---- C-phase for one s: 4 MFMA + silu + pack + shuffle-gather -> a2[s][0..1]
__device__ AI inline void c_build(const short8 (&w1f)[4], const short8& a1s,
                                  const int srcA, const int srcB, const bool selB,
                                  short8& q0, short8& q1)
{
    unsigned p[4][2];
    #pragma unroll
    for (int half = 0; half < 2; ++half) {
        floatx4 z4 = {0.f, 0.f, 0.f, 0.f};
        floatx4 c0 = __builtin_amdgcn_mfma_f32_16x16x32_bf16(w1f[2*half    ], a1s, z4, 0, 0, 0);
        floatx4 c1 = __builtin_amdgcn_mfma_f32_16x16x32_bf16(w1f[2*half + 1], a1s, z4, 0, 0, 0);
        #pragma unroll
        for (int h = 0; h < 2; ++h) {
            const floatx4& c = h ? c1 : c0;
            float sv[4];
            #pragma unroll
            for (int r = 0; r < 4; ++r) {
                const float u   = c[r] * 0.25f;                 // /sqrt(16)
                const float den = 1.f + __expf(-u);
                sv[r] = u * __builtin_amdgcn_rcpf(den) * 0.015625f; // /64
            }
            p[2*half + h][0] = cvt_pk_bf16(sv[0], sv[1]);
            p[2*half + h][1] = cvt_pk_bf16(sv[2], sv[3]);
        }
    }
    #pragma unroll
    for (int qq = 0; qq < 2; ++qq) {
        union { short8 s8; unsigned u[4]; } uu;
        #pragma unroll
        for (int w = 0; w < 4; ++w) {
            const int srcLane = (w < 2) ? srcA : srcB;
            const unsigned vA = (unsigned)__shfl((int)p[2*qq    ][w & 1], srcLane, 64);
            const unsigned vB = (unsigned)__shfl((int)p[2*qq + 1][w & 1], srcLane, 64);
            uu.u[w] = selB ? vB : vA;
        }
        if (qq == 0) q0 = uu.s8; else q1 = uu.s8;
    }
}

// ---- one g-group of the main GEMM epilogue loop ----
__device__ AI inline void d_group(const unsigned short* __restrict__ w2t,
                                  const unsigned short* __restrict__ zt,
                                  const float* __restrict__ at,
                                  const int g, const int m16, const int quad, const int par,
                                  const int o0, const int o1,
                                  const short8& a00, const short8& a01,
                                  const short8& a10, const short8& a11,
                                  float (&eacc)[2][4])
{
    float av[2][4];
    #pragma unroll
    for (int s = 0; s < 2; ++s) {
        const float4 a4v = *(const float4*)(at + g * 32 + s * 16 + quad * 4);
        av[s][0] = a4v.x; av[s][1] = a4v.y; av[s][2] = a4v.z; av[s][3] = a4v.w;
    }
    float tacc[2][4];
    #pragma unroll
    for (int s = 0; s < 2; ++s)
        #pragma unroll
        for (int r = 0; r < 4; ++r) tacc[s][r] = 0.f;

    #pragma unroll
    for (int tt = 0; tt < 8; ++tt) {
        const int t = g * 8 + tt;
        const unsigned short* wrow = w2t + (16 * t + m16) * 64;
        const short8 b20 = *(const short8*)(wrow + o0);
        const short8 b21 = *(const short8*)(wrow + o1);
        const int b_idx = (2 * tt + par) & 15;
        {
            floatx4 c = {0.f, 0.f, 0.f, 0.f};
            c = __builtin_amdgcn_mfma_f32_16x16x32_bf16(a00, b20, c, 0, 0, 0);
            c = __builtin_amdgcn_mfma_f32_16x16x32_bf16(a01, b21, c, 0, 0, 0);
            const ushort4 zu = *(const ushort4*)(zt + b_idx * 32 + quad * 4);
            tacc[0][0] = fmaf(c[0], bf2f(zu.x), tacc[0][0]);
            tacc[0][1] = fmaf(c[1], bf2f(zu.y), tacc[0][1]);
            tacc[0][2] = fmaf(c[2], bf2f(zu.z), tacc[0][2]);
            tacc[0][3] = fmaf(c[3], bf2f(zu.w), tacc[0][3]);
        }
        {
            floatx4 c = {0.f, 0.f, 0.f, 0.f};
            c = __builtin_amdgcn_mfma_f32_16x16x32_bf16(a10, b20, c, 0, 0, 0);
            c = __builtin_amdgcn_mfma_f32_16x16x32_bf16(a11, b21, c, 0, 0, 0);
            const ushort4 zu = *(const ushort4*)(zt + b_idx * 32 + 16 + quad * 4);
            tacc[1][0] = fmaf(c[0], bf2f(zu.x), tacc[1][0]);
            tacc[1][1] = fmaf(c[1], bf2f(zu.y), tacc[1][1]);
            tacc[1][2] = fmaf(c[2], bf2f(zu.z), tacc[1][2]);
            tacc[1][3] = fmaf(c[3], bf2f(zu.w), tacc[1][3]);
        }
    }
    #pragma unroll
    for (int s = 0; s < 2; ++s)
        #pragma unroll
        for (int r = 0; r < 4; ++r)
            eacc[s][r] = fmaf(av[s][r], tacc[s][r], eacc[s][r]);
}

__device__ AI inline void stage_write(unsigned short* __restrict__ zt,
                                      float* __restrict__ at, int* __restrict__ vjw,
                                      const int mst,
                                      const float4& xi0, const float4& xi1,
                                      const float4& xj0, const float4& xj1,
                                      const float4& a4, const int vj)
{
    unsigned w;
    w = cvt_pk_bf16(xi0.x, xi0.y);
    zt[ 0*32+mst] = (unsigned short)w; zt[ 1*32+mst] = (unsigned short)(w >> 16);
    w = cvt_pk_bf16(xi0.z, xi0.w);
    zt[ 2*32+mst] = (unsigned short)w; zt[ 3*32+mst] = (unsigned short)(w >> 16);
    w = cvt_pk_bf16(xi1.x, xi1.y);
    zt[ 4*32+mst] = (unsigned short)w; zt[ 5*32+mst] = (unsigned short)(w >> 16);
    w = cvt_pk_bf16(xi1.z, xi1.w);
    zt[ 6*32+mst] = (unsigned short)w; zt[ 7*32+mst] = (unsigned short)(w >> 16);
    w = cvt_pk_bf16(xj0.x, xj0.y);
    zt[ 8*32+mst] = (unsigned short)w; zt[ 9*32+mst] = (unsigned short)(w >> 16);
    w = cvt_pk_bf16(xj0.z, xj0.w);
    zt[10*32+mst] = (unsigned short)w; zt[11*32+mst] = (unsigned short)(w >> 16);
    w = cvt_pk_bf16(xj1.x, xj1.y);
    zt[12*32+mst] = (unsigned short)w; zt[13*32+mst] = (unsigned short)(w >> 16);
    w = cvt_pk_bf16(xj1.z, xj1.w);
    zt[14*32+mst] = (unsigned short)w; zt[15*32+mst] = (unsigned short)(w >> 16);
    at[0*32+mst] = a4.x; at[1*32+mst] = a4.y;
    at[2*32+mst] = a4.z; at[3*32+mst] = a4.w;
    vjw[mst] = vj;
}

__device__ AI inline short8 pack_a1(const float4& u0, const float4& u1, const bool stg)
{
    union { short8 s8; unsigned u[4]; } uu;
    if (stg) {
        uu.u[0] = cvt_pk_bf16(u0.x, u0.y);
        uu.u[1] = cvt_pk_bf16(u0.z, u0.w);
        uu.u[2] = cvt_pk_bf16(u1.x, u1.y);
        uu.u[3] = cvt_pk_bf16(u1.z, u1.w);
    } else {
        uu.u[0] = 0u; uu.u[1] = 0u; uu.u[2] = 0u; uu.u[3] = 0u;
    }
    return uu.s8;
}

__global__ __launch_bounds__(TB, 2)
void edge_kernel(
    const float* __restrict__ x,          // [N,8]
    const int*   __restrict__ ei,         // [2,E]
    const float* __restrict__ attr,       // [E,4]
    const float* __restrict__ emb,        // [E,16]
    const float* __restrict__ w1,         // [16,64]
    const float* __restrict__ w2,         // [64,512]
    float* __restrict__ edge_out,         // [E,8]
    float* __restrict__ e_sum,            // [N,8] pre-zeroed
    int E)
{
    // w2 transposed, bf16, XOR-swizzled: s_w2t[n*64 + (k ^ ((n&7)<<3))] = w2[k][n]
    __shared__ __align__(16) unsigned short s_w2t[512 * 64];          // 65536 B
    // per wave, double-buffered: z bf16 [16][32], attr f32 [4][32], vj [32]
    __shared__ __align__(16) unsigned short s_ztA[NWAVE * 2 * 512];   // 16384 B
    __shared__ __align__(16) float          s_atA[NWAVE * 2 * 128];   //  8192 B
    __shared__ int                          s_vjA[NWAVE * 2 * 32];    //  2048 B
    // total = 92160 B (1 block/CU; occupancy route closed — see header)

    const int tid  = threadIdx.x;
    const int wave = tid >> 6;
    const int lane = tid & 63;
    const int m16  = lane & 15;
    const int quad = lane >> 4;
    const int par  = m16 >> 3;

    // ---- stage w2 transposed+swizzled to bf16 ----
    for (int idx = tid; idx < 512 * 64; idx += TB) {
        const int n = idx & 511, k = idx >> 9;
        s_w2t[n * 64 + (k ^ ((n & 7) << 3))] = f2bf(w2[k * 512 + n]);
    }
    __syncthreads();   // only barrier; steady loop is wave-private

    // ---- layer-1 w1 fragments (zero-padded K 16->32) ----
    short8 w1f[4];
    #pragma unroll
    for (int mt = 0; mt < 4; ++mt) {
        short8 f;
        if (quad < 2) {
            #pragma unroll
            for (int j = 0; j < 8; ++j)
                f[j] = (short)f2bf(w1[(quad * 8 + j) * 64 + mt * 16 + m16]);
        } else {
            #pragma unroll
            for (int j = 0; j < 8; ++j) f[j] = 0;
        }
        w1f[mt] = f;
    }

    unsigned short* ztw0 = s_ztA + (wave * 2    ) * 512;
    unsigned short* ztw1 = s_ztA + (wave * 2 + 1) * 512;
    float*          atw0 = s_atA + (wave * 2    ) * 128;
    float*          atw1 = s_atA + (wave * 2 + 1) * 128;
    int*            vjw0 = s_vjA + (wave * 2    ) * 32;
    int*            vjw1 = s_vjA + (wave * 2 + 1) * 32;

    const int  wid = blockIdx.x * NWAVE + wave;
    const int  nw  = NBLK * NWAVE;
    const int  ntiles = E >> 5;   // E divisible by 32 (800000)
    const bool stg = (quad < 2);
    const int  mst = quad * 16 + m16;
    const bool selB = (quad & 2);

    const int srcA = m16 + 16 * ((2 * quad) & 3);
    const int srcB = m16 + 16 * ((2 * quad + 1) & 3);
    const int swz = (m16 & 7) << 3;
    const int o0  = (quad * 8) ^ swz;
    const int o1  = o0 ^ 32;

    // ---- PROLOG: fully stage + C-phase tile wid into buf0; prefetch ei ----
    int viC = 0, vjC = 0;       // ei of the NEXT tile to stage
    short8 a2c[2][2];
    {
        float4 xi0, xi1, xj0, xj1, a4;
        float4 em0a, em0b, em1a, em1b;
        if (stg) {
            const int e0 = (wid << 5) + mst;
            const int vi = ei[e0];
            const int vj = ei[E + e0];
            xi0 = *(const float4*)(x + (size_t)vi * 8);
            xi1 = *(const float4*)(x + (size_t)vi * 8 + 4);
            xj0 = *(const float4*)(x + (size_t)vj * 8);
            xj1 = *(const float4*)(x + (size_t)vj * 8 + 4);
            a4  = *(const float4*)(attr + (size_t)e0 * 4);
            const float* ep0 = emb + (size_t)((wid << 5) + m16) * 16 + quad * 8;
            em0a = *(const float4*)ep0;
            em0b = *(const float4*)(ep0 + 4);
            const float* ep1 = emb + (size_t)((wid << 5) + 16 + m16) * 16 + quad * 8;
            em1a = *(const float4*)ep1;
            em1b = *(const float4*)(ep1 + 4);
            stage_write(ztw0, atw0, vjw0, mst, xi0, xi1, xj0, xj1, a4, vj);
            const int t1 = (wid + nw < ntiles) ? (wid + nw) : wid;
            const int e1 = (t1 << 5) + mst;
            viC = ei[e1];
            vjC = ei[E + e1];
        }
        const short8 a1s0 = pack_a1(em0a, em0b, stg);
        const short8 a1s1 = pack_a1(em1a, em1b, stg);
        c_build(w1f, a1s0, srcA, srcB, selB, a2c[0][0], a2c[0][1]);
        c_build(w1f, a1s1, srcA, srcB, selB, a2c[1][0], a2c[1][1]);
    }

    int cur = 0;
    for (int tile = wid; tile < ntiles; tile += nw) {
        const int base  = tile << 5;
        const int tn_cl = (tile + nw < ntiles) ? (tile + nw) : tile;
        unsigned short* zt_c = cur ? ztw1 : ztw0;
        unsigned short* zt_n = cur ? ztw0 : ztw1;
        float*          at_c = cur ? atw1 : atw0;
        float*          at_n = cur ? atw0 : atw1;
        int*            vj_c = cur ? vjw1 : vjw0;
        int*            vj_n = cur ? vjw0 : vjw1;

        // ---- S1: issue next-tile global loads (latency hides under g0/g1) ----
        float4 xi0, xi1, xj0, xj1, a4;
        float4 em0a, em0b, em1a, em1b;
        if (stg) {
            const int en = (tn_cl << 5) + mst;
            xi0 = *(const float4*)(x + (size_t)viC * 8);
            xi1 = *(const float4*)(x + (size_t)viC * 8 + 4);
            xj0 = *(const float4*)(x + (size_t)vjC * 8);
            xj1 = *(const float4*)(x + (size_t)vjC * 8 + 4);
            a4  = *(const float4*)(attr + (size_t)en * 4);
            const float* ep0 = emb + (size_t)((tn_cl << 5) + m16) * 16 + quad * 8;
            em0a = *(const float4*)ep0;
            em0b = *(const float4*)(ep0 + 4);
            const float* ep1 = emb + (size_t)((tn_cl << 5) + 16 + m16) * 16 + quad * 8;
            em1a = *(const float4*)ep1;
            em1b = *(const float4*)(ep1 + 4);
        }

        float eacc[2][4];
        #pragma unroll
        for (int s = 0; s < 2; ++s)
            #pragma unroll
            for (int r = 0; r < 4; ++r) eacc[s][r] = 0.f;

        // ---- D g0, g1 (current tile) ----
        d_group(s_w2t, zt_c, at_c, 0, m16, quad, par, o0, o1,
                a2c[0][0], a2c[0][1], a2c[1][0], a2c[1][1], eacc);
        d_group(s_w2t, zt_c, at_c, 1, m16, quad, par, o0, o1,
                a2c[0][0], a2c[0][1], a2c[1][0], a2c[1][1], eacc);

        // ---- S3: consume loads -> buf nxt; prefetch ei two tiles ahead ----
        if (stg) {
            stage_write(zt_n, at_n, vj_n, mst, xi0, xi1, xj0, xj1, a4, vjC);
            const int t2 = (tile + 2 * nw < ntiles) ? (tile + 2 * nw) : tn_cl;
            const int e2 = (t2 << 5) + mst;
            viC = ei[e2];
            vjC = ei[E + e2];
        }
        const short8 a1s0 = pack_a1(em0a, em0b, stg);
        const short8 a1s1 = pack_a1(em1a, em1b, stg);

        // ---- C(s0) for next tile, then D g2; C(s1), then D g3 ----
        short8 a2n[2][2];
        c_build(w1f, a1s0, srcA, srcB, selB, a2n[0][0], a2n[0][1]);
        d_group(s_w2t, zt_c, at_c, 2, m16, quad, par, o0, o1,
                a2c[0][0], a2c[0][1], a2c[1][0], a2c[1][1], eacc);
        c_build(w1f, a1s1, srcA, srcB, selB, a2n[1][0], a2n[1][1]);
        d_group(s_w2t, zt_c, at_c, 3, m16, quad, par, o0, o1,
                a2c[0][0], a2c[0][1], a2c[1][0], a2c[1][1], eacc);

        // ---- E: reduce ab-parity, write edge_out + atomic e_sum ----
        #pragma unroll
        for (int s = 0; s < 2; ++s)
            #pragma unroll
            for (int r = 0; r < 4; ++r)
                eacc[s][r] += __shfl_xor(eacc[s][r], 8, 64);

        if (m16 < 8) {
            #pragma unroll
            for (int s = 0; s < 2; ++s) {
                const int4 vjq = *(const int4*)(vj_c + s * 16 + quad * 4);
                const int vjr[4] = {vjq.x, vjq.y, vjq.z, vjq.w};
                #pragma unroll
                for (int r = 0; r < 4; ++r) {
                    const int e = base + s * 16 + quad * 4 + r;
                    edge_out[(size_t)e * 8 + m16] = eacc[s][r];
                    atomicAdd(e_sum + (size_t)vjr[r] * 8 + m16, eacc[s][r]);
                }
            }
        }

        // ---- rotate a2 double-buffer ----
        a2c[0][0] = a2n[0][0]; a2c[0][1] = a2n[0][1];
        a2c[1][0] = a2n[1][0]; a2c[1][1] = a2n[1][1];
        cur ^= 1;
    }
}

__global__ __launch_bounds__(256) void node_kernel(
    const float* __restrict__ x,       // [N,8]
    const float* __restrict__ e_sum,   // [N,8]
    const float* __restrict__ w_node,  // [8,8,16]
    float* __restrict__ x_out,         // [N,16]
    int N)
{
    __shared__ float s_w[8 * 8 * 16];
    for (int idx = threadIdx.x; idx < 1024; idx += 256) s_w[idx] = w_node[idx];
    __syncthreads();

    const int n = blockIdx.x * 256 + threadIdx.x;
    if (n >= N) return;

    float xa[8], eb[8];
    #pragma unroll
    for (int a = 0; a < 8; ++a) xa[a] = x[(size_t)n * 8 + a];
    #pragma unroll
    for (int b = 0; b < 8; ++b) eb[b] = e_sum[(size_t)n * 8 + b];

    float out[16];
    #pragma unroll
    for (int k = 0; k < 16; ++k) out[k] = 0.f;

    const float4* wv = (const float4*)s_w;
    #pragma unroll
    for (int a = 0; a < 8; ++a) {
        #pragma unroll
        for (int b = 0; b < 8; ++b) {
            const float t = xa[a] * eb[b] * 0.125f;
            #pragma unroll
            for (int k4 = 0; k4 < 4; ++k4) {
                const float4 w = wv[(a * 8 + b) * 4 + k4];
                out[k4 * 4 + 0] = fmaf(t, w.x, out[k4 * 4 + 0]);
                out[k4 * 4 + 1] = fmaf(t, w.y, out[k4 * 4 + 1]);
                out[k4 * 4 + 2] = fmaf(t, w.z, out[k4 * 4 + 2]);
                out[k4 * 4 + 3] = fmaf(t, w.w, out[k4 * 4 + 3]);
            }
        }
    }

    float4* xo = (float4*)(x_out + (size_t)n * 16);
    #pragma unroll
    for (int k4 = 0; k4 < 4; ++k4)
        xo[k4] = make_float4(out[k4 * 4 + 0], out[k4 * 4 + 1],
                             out[k4 * 4 + 2], out[k4 * 4 + 3]);
}

extern "C" void kernel_launch(void* const* d_in, const int* in_sizes, int n_in,
                              void* d_out, int out_size, void* d_ws, size_t ws_size,
                              hipStream_t stream) {
    const float* x      = (const float*)d_in[0];
    const int*   ei     = (const int*)d_in[1];
    const float* attr   = (const float*)d_in[2];
    const float* emb    = (const float*)d_in[3];
    const float* w1     = (const float*)d_in[4];
    const float* w2     = (const float*)d_in[5];
    const float* w_node = (const float*)d_in[6];

    const int N = in_sizes[0] / 8;   // 50000
    const int E = in_sizes[2] / 4;   // 800000

    float* x_out    = (float*)d_out;                   // [N,16]
    float* edge_out = (float*)d_out + (size_t)N * 16;  // [E,8]
    float* e_sum    = (float*)d_ws;                    // [N,8]

    hipMemsetAsync(e_sum, 0, (size_t)N * 8 * sizeof(float), stream);

    edge_kernel<<<NBLK, TB, 0, stream>>>(x, ei, attr, emb, w1, w2,
                                         edge_out, e_sum, E);

    node_kernel<<<(N + 255) / 256, 256, 0, stream>>>(x, e_sum, w_node, x_out, N);
}